// Round 4
// baseline (273.648 us; speedup 1.0000x reference)
//
#include <hip/hip_runtime.h>

#define IMG   512
#define NA    90
#define DET   729
#define NPIX  (IMG*IMG)
#define HW    514            // halo'd NHWC width/height
#define QW    514            // quad image width
#define HBELEMS (HW*HW*32)   // elems per halo'd NHWC bf16 buffer

// conv LDS tile
#define TROWS 6
#define TPIX  66
#define PIXB  80                 // padded bytes per pixel slot (64 data + 16 pad)
#define ROWB  (TPIX*PIXB)        // 5280
#define NCHUNK (TROWS*TPIX*4)    // 1584 16B-chunks

typedef __attribute__((ext_vector_type(8))) short     bf16x8;
typedef __attribute__((ext_vector_type(8))) unsigned short ushort8;
typedef __attribute__((ext_vector_type(4))) float     f32x4;

__device__ __forceinline__ unsigned short f2b(float f) {
    unsigned int u = __builtin_bit_cast(unsigned int, f);
    return (unsigned short)((u + 0x7FFFu + ((u >> 16) & 1u)) >> 16);
}
__device__ __forceinline__ float b2f(unsigned short h) {
    return __builtin_bit_cast(float, (unsigned int)h << 16);
}

// ---------------- prep0: trig table (block 0) + packed bf16 quad image ----------------
// quad[q] = uint2{ b00 | b01<<16 , b10 | b11<<16 }
__global__ void prep0_k(const float* __restrict__ theta, const float* __restrict__ img,
                        float* __restrict__ trig, uint2* __restrict__ quad) {
    if (blockIdx.x == 0) {
        int i = threadIdx.x;
        if (i < NA) {
            float t = theta[i];
            trig[2*i]   = cosf(t);
            trig[2*i+1] = sinf(t);
        }
        return;
    }
    int q = (blockIdx.x - 1) * 256 + threadIdx.x;
    if (q >= QW*QW) return;
    int qy = q / QW, qx = q - qy*QW;
    auto val = [&](int r, int c) -> float {
        return (r >= 1 && r <= 512 && c >= 1 && c <= 512) ? img[((r-1) << 9) + (c-1)] : 0.f;
    };
    unsigned int lo = (unsigned int)f2b(val(qy, qx))   | ((unsigned int)f2b(val(qy, qx+1))   << 16);
    unsigned int hi = (unsigned int)f2b(val(qy+1, qx)) | ((unsigned int)f2b(val(qy+1, qx+1)) << 16);
    quad[q] = make_uint2(lo, hi);
}

// ---------------- radon forward: wave per (angle,det), chord-clipped, bf16-quad gathers ----------------
__global__ __launch_bounds__(256) void radon_fwd_k(const uint2* __restrict__ quad,
        const float* __restrict__ trig, float* __restrict__ sino) {
    int wid  = threadIdx.x >> 6;
    int lane = threadIdx.x & 63;
    int idx  = blockIdx.x * 4 + wid;
    if (idx >= NA*DET) return;
    int a = idx / DET, d = idx - a*DET;
    float cs = trig[2*a], sn = trig[2*a+1];          // sn >= 0 for theta in [0,pi)
    float sd = (float)d - 364.0f;
    float bx = 255.5f + sd*cs;   // px = bx - sj*sn
    float by = 255.5f + sd*sn;   // py = by + sj*cs

    // valid sj range: px in [-1,512] and py in [-1,512]
    float inv_sn = 1.0f / sn;
    float ta = (bx - 512.0f) * inv_sn, tb = (bx + 1.0f) * inv_sn;
    float lo = fminf(ta, tb), hi = fmaxf(ta, tb);
    float inv_cs = 1.0f / cs;
    float tc = (-1.0f - by) * inv_cs, td = (512.0f - by) * inv_cs;
    lo = fmaxf(lo, fminf(tc, td));
    hi = fminf(hi, fmaxf(tc, td));
    float jlo_f = fminf(fmaxf(lo + 364.0f, 0.0f), 729.0f);
    float jhi_f = fminf(fmaxf(hi + 364.0f, -1.0f), 728.0f);
    int jlo = (int)ceilf(jlo_f);
    int jhi = (int)floorf(jhi_f);

    auto samp = [&](float pxr, float pyr) -> float {
        float cx = fminf(fmaxf(pxr, -1.0f), 512.0f);
        float cy = fminf(fmaxf(pyr, -1.0f), 512.0f);
        float fx0 = floorf(cx), fy0 = floorf(cy);
        float fx = cx - fx0, fy = cy - fy0;
        int qi = (int)fy0 * QW + (int)fx0 + (QW + 1);
        uint2 q = quad[qi];
        float v00 = __builtin_bit_cast(float, q.x << 16);
        float v01 = __builtin_bit_cast(float, q.x & 0xffff0000u);
        float v10 = __builtin_bit_cast(float, q.y << 16);
        float v11 = __builtin_bit_cast(float, q.y & 0xffff0000u);
        float top = v00 + fx*(v01 - v00);
        float bot = v10 + fx*(v11 - v10);
        return top + fy*(bot - top);
    };

    float acc = 0.f;
    int j = jlo + lane;
    float s0 = (float)(j - 364);
    float px1 = bx - s0*sn,          py1 = by + s0*cs;
    float px2 = px1 - 64.0f*sn,      py2 = py1 + 64.0f*cs;
    float dx128 = -128.0f*sn,        dy128 = 128.0f*cs;
    for (; j + 64 <= jhi; j += 128) {
        acc += samp(px1, py1) + samp(px2, py2);
        px1 += dx128; py1 += dy128;
        px2 += dx128; py2 += dy128;
    }
    if (j <= jhi) acc += samp(px1, py1);

    for (int off = 32; off; off >>= 1) acc += __shfl_down(acc, off);
    if (lane == 0) sino[idx] = acc;
}

// ---------------- ramp filter (direct conv == FFT path) + subtract measurement ----------------
__global__ __launch_bounds__(256) void filter_k(const float* __restrict__ sino,
        const float* __restrict__ meas, float* __restrict__ diff) {
    __shared__ float prow[DET + 2*728];
    __shared__ float invsq[364];
    int a = blockIdx.x / 3, seg = blockIdx.x - 3*a;
    for (int t = threadIdx.x; t < DET + 2*728; t += 256)
        prow[t] = (t >= 728 && t < 728 + DET) ? sino[a*DET + (t - 728)] : 0.f;
    const float cc = -2.0f / (3.14159265358979323846f * 3.14159265358979323846f);
    for (int k = threadIdx.x; k < 364; k += 256) {
        float dlt = (float)(2*k + 1);
        invsq[k] = cc / (dlt * dlt);
    }
    __syncthreads();
    const float scale = 3.14159265358979323846f / 180.0f;  // pi/(2*90)
    int i = seg*243 + threadIdx.x;
    if (threadIdx.x < 243) {
        const float* p = prow + 728 + i;
        float acc = 0.5f * p[0];
        #pragma unroll 4
        for (int k = 0; k < 364; k++) {
            int dlt = 2*k + 1;
            acc += (p[-dlt] + p[dlt]) * invsq[k];
        }
        diff[a*DET + i] = acc * scale - meas[a*DET + i];
    }
}

// ---------------- build float2 pairs (diff[i], diff[i+1]) for backprojection ----------------
__global__ void pair_k(const float* __restrict__ diff, float2* __restrict__ pair) {
    int i = blockIdx.x * 256 + threadIdx.x;
    if (i >= NA*DET) return;
    int col = i - (i / DET) * DET;
    float b = (col == DET-1) ? 0.f : diff[i + 1];
    pair[i] = make_float2(diff[i], b);
}

// ---------------- backprojection fused with x_input = x - lambda*bp ----------------
__global__ __launch_bounds__(256) void backproj_k(const float2* __restrict__ pair,
        const float* __restrict__ trig, const float* __restrict__ x,
        const float* __restrict__ lam, float* __restrict__ xin) {
    int pix = blockIdx.x * 256 + threadIdx.x;
    float X = (float)(pix & 511) - 255.5f;
    float Y = (float)(pix >> 9) - 255.5f;
    float acc = 0.f;
    for (int a = 0; a < NA; a++) {
        float pos = X*trig[2*a] + Y*trig[2*a+1] + 364.0f;
        if (pos >= 0.f && pos <= 728.f) {
            int i0 = (int)pos;
            if (i0 > 727) i0 = 727;
            float w = pos - (float)i0;
            float2 p = pair[a*DET + i0];
            acc += p.x + w*(p.y - p.x);
        }
    }
    xin[pix] = x[pix] - lam[0] * acc;
}

// ---------------- prep1: zero halo rings (t<8208) + weight prep (rest) ----------------
__global__ void prep1_k(unsigned short* __restrict__ hb0, size_t hbstride_elems,
                        const float* __restrict__ w0, const float* __restrict__ w1,
                        const float* __restrict__ w2, const float* __restrict__ w3,
                        unsigned short* __restrict__ wbuf) {
    int t = blockIdx.x * 256 + threadIdx.x;
    if (t < 4*2052) {
        int b = t / 2052, r = t - b*2052;
        int py, px;
        if      (r < 514)  { py = 0;            px = r; }
        else if (r < 1028) { py = 513;          px = r - 514; }
        else if (r < 1540) { py = r - 1028 + 1; px = 0; }
        else               { py = r - 1540 + 1; px = 513; }
        unsigned short* p = hb0 + b*hbstride_elems + ((size_t)py*HW + px)*32;
        uint4 z = make_uint4(0,0,0,0);
        ((uint4*)p)[0] = z; ((uint4*)p)[1] = z; ((uint4*)p)[2] = z; ((uint4*)p)[3] = z;
        return;
    }
    int tid = t - 4*2052;
    if (tid >= 4*9216) return;
    int L = tid / 9216, r = tid - L*9216;
    int tt = r >> 10, o = (r >> 5) & 31, i = r & 31;
    const float* s = (L == 0) ? w0 : (L == 1) ? w1 : (L == 2) ? w2 : w3;
    wbuf[tid] = f2b(s[o*288 + i*9 + tt]);
}

// ---------------- conv_D: 1 -> 32, f32 direct; writes bf16 NHWC halo'd ----------------
__global__ __launch_bounds__(256) void convD_k(const float* __restrict__ xin,
        const float* __restrict__ wD, unsigned short* __restrict__ out_nhwc) {
    int pix = blockIdx.x * 256 + threadIdx.x;
    int y = pix >> 9, x = pix & 511;
    float v[9];
    #pragma unroll
    for (int dy = -1; dy <= 1; dy++)
        #pragma unroll
        for (int dx = -1; dx <= 1; dx++) {
            int yy = y + dy, xx = x + dx;
            v[(dy+1)*3 + dx+1] = (yy >= 0 && yy < 512 && xx >= 0 && xx < 512)
                                 ? xin[(yy << 9) + xx] : 0.f;
        }
    unsigned int packed[16];
    #pragma unroll
    for (int oc = 0; oc < 32; ++oc) {
        float acc = 0.f;
        #pragma unroll
        for (int t = 0; t < 9; t++) acc = fmaf(v[t], wD[oc*9 + t], acc);
        unsigned int b = f2b(acc);
        if (oc & 1) packed[oc >> 1] |= b << 16; else packed[oc >> 1] = b;
    }
    uint4* dst = (uint4*)(out_nhwc + ((size_t)(y+1)*HW + (x+1))*32);
    dst[0] = make_uint4(packed[0],  packed[1],  packed[2],  packed[3]);
    dst[1] = make_uint4(packed[4],  packed[5],  packed[6],  packed[7]);
    dst[2] = make_uint4(packed[8],  packed[9],  packed[10], packed[11]);
    dst[3] = make_uint4(packed[12], packed[13], packed[14], packed[15]);
}

// ---------------- MFMA conv 32->32 with LDS-staged input tile ----------------
// MODE: 0 plain->out0 | 1 relu->out0 | 2 dual: raw->out0, softthr->out1
//       | 3 symloss: - aux(bf16 NHWC) -> s1,s2 (f32 NCHW)
template<int MODE>
__global__ __launch_bounds__(256) void convM_k(const unsigned short* __restrict__ in,
        const unsigned short* __restrict__ wb,
        unsigned short* __restrict__ out0, unsigned short* __restrict__ out1,
        const float* __restrict__ thr_p,
        const unsigned short* __restrict__ aux, float* __restrict__ s1, float* __restrict__ s2) {
    __shared__ __align__(16) unsigned char smem[TROWS*ROWB];   // 31680 B
    int wid  = threadIdx.x >> 6;
    int lane = threadIdx.x & 63;
    int by = blockIdx.x >> 3, bx = blockIdx.x & 7;
    int y0 = by*4;
    int y  = y0 + wid;            // 0..511
    int x0 = bx*64;
    int lpix = lane & 15;
    int kq16 = (lane >> 4) * 16;  // byte offset of this lane's K-slice within a pixel
    int k8   = (lane >> 4) * 8;

    // ---- issue staging loads (global -> regs) ----
    uint4 stg[7];
    #pragma unroll
    for (int it = 0; it < 7; it++) {
        int c = threadIdx.x + it*256;
        if (c < NCHUNK) {
            int r = c / (TPIX*4);
            int rem = c - r*(TPIX*4);
            int p = rem >> 2, q = rem & 3;
            stg[it] = *(const uint4*)(in + ((size_t)(y0 + r)*HW + x0 + p)*32 + q*8);
        }
    }

    // ---- weights (A-frags), overlap with staging latency ----
    bf16x8 A[9][2];
    #pragma unroll
    for (int t = 0; t < 9; t++)
        #pragma unroll
        for (int ob = 0; ob < 2; ob++)
            A[t][ob] = *(const bf16x8*)(wb + t*1024 + (ob*16 + lpix)*32 + k8);

    // ---- write staged chunks to LDS ----
    #pragma unroll
    for (int it = 0; it < 7; it++) {
        int c = threadIdx.x + it*256;
        if (c < NCHUNK) {
            int r = c / (TPIX*4);
            int rem = c - r*(TPIX*4);
            int p = rem >> 2, q = rem & 3;
            *(uint4*)(smem + r*ROWB + p*PIXB + q*16) = stg[it];
        }
    }
    __syncthreads();

    f32x4 acc[2][4];
    #pragma unroll
    for (int ob = 0; ob < 2; ob++)
        #pragma unroll
        for (int p = 0; p < 4; p++) acc[ob][p] = (f32x4){0.f,0.f,0.f,0.f};

    #pragma unroll
    for (int p = 0; p < 4; p++) {
        #pragma unroll
        for (int dy = 0; dy < 3; dy++) {
            const unsigned char* rp = smem + (wid + dy)*ROWB + kq16;
            #pragma unroll
            for (int dx = 0; dx < 3; dx++) {
                bf16x8 B = *(const bf16x8*)(rp + (p*16 + lpix + dx)*PIXB);
                int t = dy*3 + dx;
                acc[0][p] = __builtin_amdgcn_mfma_f32_16x16x32_bf16(A[t][0], B, acc[0][p], 0,0,0);
                acc[1][p] = __builtin_amdgcn_mfma_f32_16x16x32_bf16(A[t][1], B, acc[1][p], 0,0,0);
            }
        }
    }

    int prow = (lane >> 4) * 4;
    float thr = (MODE == 2) ? thr_p[0] : 0.f;
    #pragma unroll
    for (int ob = 0; ob < 2; ob++)
        #pragma unroll
        for (int p = 0; p < 4; p++) {
            f32x4 a = acc[ob][p];
            if (MODE == 3) {
                size_t aoff = ((size_t)(y+1)*HW + (x0 + 1 + p*16 + lpix))*32 + ob*16 + prow;
                ushort4 av = *(const ushort4*)(aux + aoff);
                int pix = (y << 9) + x0 + p*16 + lpix;
                float w0v = a[0] - b2f(av.x);
                float w1v = a[1] - b2f(av.y);
                float w2v = a[2] - b2f(av.z);
                float w3v = a[3] - b2f(av.w);
                int ocb = ob*16 + prow;
                s1[(size_t)(ocb+0)*NPIX + pix] = w0v; s2[(size_t)(ocb+0)*NPIX + pix] = w0v;
                s1[(size_t)(ocb+1)*NPIX + pix] = w1v; s2[(size_t)(ocb+1)*NPIX + pix] = w1v;
                s1[(size_t)(ocb+2)*NPIX + pix] = w2v; s2[(size_t)(ocb+2)*NPIX + pix] = w2v;
                s1[(size_t)(ocb+3)*NPIX + pix] = w3v; s2[(size_t)(ocb+3)*NPIX + pix] = w3v;
            } else {
                size_t off = ((size_t)(y+1)*HW + (x0 + 1 + p*16 + lpix))*32 + ob*16 + prow;
                if (MODE == 1) {
                    #pragma unroll
                    for (int r = 0; r < 4; r++) a[r] = fmaxf(a[r], 0.f);
                }
                *(ushort4*)(out0 + off) = make_ushort4(f2b(a[0]), f2b(a[1]), f2b(a[2]), f2b(a[3]));
                if (MODE == 2) {
                    float st[4];
                    #pragma unroll
                    for (int r = 0; r < 4; r++)
                        st[r] = copysignf(fmaxf(fabsf(a[r]) - thr, 0.f), a[r]);
                    *(ushort4*)(out1 + off) = make_ushort4(f2b(st[0]), f2b(st[1]), f2b(st[2]), f2b(st[3]));
                }
            }
        }
}

// ---------------- conv_G: 32 -> 1 direct from bf16 NHWC, + xin ----------------
__global__ __launch_bounds__(256) void convG_k(const unsigned short* __restrict__ xb,
        const float* __restrict__ wG, const float* __restrict__ xin,
        float* __restrict__ out) {
    int pix = blockIdx.x * 256 + threadIdx.x;
    int y = pix >> 9, x = pix & 511;
    float acc = 0.f;
    #pragma unroll
    for (int dy = -1; dy <= 1; dy++)
        #pragma unroll
        for (int dx = -1; dx <= 1; dx++) {
            int t = (dy+1)*3 + (dx+1);
            const unsigned short* bp = xb + ((size_t)(y+dy+1)*HW + (x+dx+1))*32;
            #pragma unroll
            for (int c8 = 0; c8 < 4; c8++) {
                ushort8 vv = *(const ushort8*)(bp + c8*8);
                #pragma unroll
                for (int e = 0; e < 8; e++)
                    acc = fmaf(b2f(vv[e]), wG[(c8*8 + e)*9 + t], acc);
            }
        }
    out[pix] = acc + xin[pix];
}

extern "C" void kernel_launch(void* const* d_in, const int* in_sizes, int n_in,
                              void* d_out, int out_size, void* d_ws, size_t ws_size,
                              hipStream_t stream) {
    const float* x     = (const float*)d_in[0];
    const float* theta = (const float*)d_in[1];
    const float* meas  = (const float*)d_in[2];
    const float* lam   = (const float*)d_in[3];
    const float* thr   = (const float*)d_in[4];
    const float* wD    = (const float*)d_in[5];
    const float* w1f   = (const float*)d_in[6];
    const float* w2f   = (const float*)d_in[7];
    const float* w1b   = (const float*)d_in[8];
    const float* w2b   = (const float*)d_in[9];
    const float* wG    = (const float*)d_in[10];

    char* ws = (char*)d_ws;
    const size_t HBB = (size_t)HBELEMS * 2;          // bytes per halo'd bf16 buffer
    unsigned short* HB1 = (unsigned short*)(ws);
    unsigned short* HB2 = (unsigned short*)(ws + HBB);
    unsigned short* HB3 = (unsigned short*)(ws + 2*HBB);
    unsigned short* HB4 = (unsigned short*)(ws + 3*HBB);
    // radon scratch aliases: sino/diff/pair in HB2 (dead until h1), quad in HB3 (dead until xf)
    float*  sino  = (float*)(ws + HBB);
    float*  diff  = (float*)(ws + HBB + 262464);
    float2* dpair = (float2*)(ws + HBB + 524928);
    uint2*  quad  = (uint2*)(ws + 2*HBB);
    float* xin  = (float*)(ws + 4*HBB);
    float* trig = (float*)(ws + 4*HBB + 1048576);
    unsigned short* wbuf = (unsigned short*)(ws + 4*HBB + 1049600);

    float* P  = (float*)d_out;        // x_pred  (NPIX)
    float* S1 = P + NPIX;             // symloss #1 (32*NPIX)
    float* S2 = S1 + 32*NPIX;         // symloss #2 (32*NPIX)

    prep0_k<<<1 + (QW*QW + 255)/256, 256, 0, stream>>>(theta, x, trig, quad);
    radon_fwd_k<<<(NA*DET + 3)/4, 256, 0, stream>>>(quad, trig, sino);
    filter_k<<<NA*3, 256, 0, stream>>>(sino, meas, diff);
    pair_k<<<(NA*DET + 255)/256, 256, 0, stream>>>(diff, dpair);
    backproj_k<<<NPIX/256, 256, 0, stream>>>(dpair, trig, x, lam, xin);
    prep1_k<<<(4*2052 + 4*9216 + 255)/256, 256, 0, stream>>>(HB1, HBELEMS,
                                                             w1f, w2f, w1b, w2b, wbuf);

    convD_k<<<NPIX/256, 256, 0, stream>>>(xin, wD, HB1);                           // x_D -> HB1 (persists)
    convM_k<1><<<1024, 256, 0, stream>>>(HB1, wbuf + 0*9216, HB2, nullptr,
                                         nullptr, nullptr, nullptr, nullptr);      // h1 -> HB2
    convM_k<2><<<1024, 256, 0, stream>>>(HB2, wbuf + 1*9216, HB3, HB4,
                                         thr, nullptr, nullptr, nullptr);          // xf -> HB3, st -> HB4
    convM_k<1><<<1024, 256, 0, stream>>>(HB4, wbuf + 2*9216, HB2, nullptr,
                                         nullptr, nullptr, nullptr, nullptr);      // h2 -> HB2
    convM_k<0><<<1024, 256, 0, stream>>>(HB2, wbuf + 3*9216, HB4, nullptr,
                                         nullptr, nullptr, nullptr, nullptr);      // xb -> HB4
    convG_k<<<NPIX/256, 256, 0, stream>>>(HB4, wG, xin, P);                        // x_pred
    convM_k<1><<<1024, 256, 0, stream>>>(HB3, wbuf + 2*9216, HB2, nullptr,
                                         nullptr, nullptr, nullptr, nullptr);      // h3 -> HB2
    convM_k<3><<<1024, 256, 0, stream>>>(HB2, wbuf + 3*9216, nullptr, nullptr,
                                         nullptr, HB1, S1, S2);                    // symloss
}

// Round 5
// 232.222 us; speedup vs baseline: 1.1784x; 1.1784x over previous
//
#include <hip/hip_runtime.h>

#define IMG   512
#define NA    90
#define DET   729
#define NPIX  (IMG*IMG)
#define HW    514            // halo'd NHWC width/height
#define QW    514            // quad image width
#define HBELEMS (HW*HW*32)   // elems per halo'd NHWC bf16 buffer

typedef __attribute__((ext_vector_type(8))) short     bf16x8;
typedef __attribute__((ext_vector_type(8))) unsigned short ushort8;
typedef __attribute__((ext_vector_type(4))) float     f32x4;

__device__ __forceinline__ unsigned short f2b(float f) {
    unsigned int u = __builtin_bit_cast(unsigned int, f);
    return (unsigned short)((u + 0x7FFFu + ((u >> 16) & 1u)) >> 16);
}
__device__ __forceinline__ float b2f(unsigned short h) {
    return __builtin_bit_cast(float, (unsigned int)h << 16);
}

// ---------------- prep0: trig table (block 0) + packed bf16 quad image ----------------
__global__ void prep0_k(const float* __restrict__ theta, const float* __restrict__ img,
                        float* __restrict__ trig, uint2* __restrict__ quad) {
    if (blockIdx.x == 0) {
        int i = threadIdx.x;
        if (i < NA) {
            float t = theta[i];
            trig[2*i]   = cosf(t);
            trig[2*i+1] = sinf(t);
        }
        return;
    }
    int q = (blockIdx.x - 1) * 256 + threadIdx.x;
    if (q >= QW*QW) return;
    int qy = q / QW, qx = q - qy*QW;
    auto val = [&](int r, int c) -> float {
        return (r >= 1 && r <= 512 && c >= 1 && c <= 512) ? img[((r-1) << 9) + (c-1)] : 0.f;
    };
    unsigned int lo = (unsigned int)f2b(val(qy, qx))   | ((unsigned int)f2b(val(qy, qx+1))   << 16);
    unsigned int hi = (unsigned int)f2b(val(qy+1, qx)) | ((unsigned int)f2b(val(qy+1, qx+1)) << 16);
    quad[q] = make_uint2(lo, hi);
}

// ---------------- radon forward: wave per (angle,det), chord-clipped, bf16-quad gathers ----------------
__global__ __launch_bounds__(256) void radon_fwd_k(const uint2* __restrict__ quad,
        const float* __restrict__ trig, float* __restrict__ sino) {
    int wid  = threadIdx.x >> 6;
    int lane = threadIdx.x & 63;
    int idx  = blockIdx.x * 4 + wid;
    if (idx >= NA*DET) return;
    int a = idx / DET, d = idx - a*DET;
    float cs = trig[2*a], sn = trig[2*a+1];          // sn >= 0 for theta in [0,pi)
    float sd = (float)d - 364.0f;
    float bx = 255.5f + sd*cs;   // px = bx - sj*sn
    float by = 255.5f + sd*sn;   // py = by + sj*cs

    float inv_sn = 1.0f / sn;
    float ta = (bx - 512.0f) * inv_sn, tb = (bx + 1.0f) * inv_sn;
    float lo = fminf(ta, tb), hi = fmaxf(ta, tb);
    float inv_cs = 1.0f / cs;
    float tc = (-1.0f - by) * inv_cs, td = (512.0f - by) * inv_cs;
    lo = fmaxf(lo, fminf(tc, td));
    hi = fminf(hi, fmaxf(tc, td));
    float jlo_f = fminf(fmaxf(lo + 364.0f, 0.0f), 729.0f);
    float jhi_f = fminf(fmaxf(hi + 364.0f, -1.0f), 728.0f);
    int jlo = (int)ceilf(jlo_f);
    int jhi = (int)floorf(jhi_f);

    auto samp = [&](float pxr, float pyr) -> float {
        float cx = fminf(fmaxf(pxr, -1.0f), 512.0f);
        float cy = fminf(fmaxf(pyr, -1.0f), 512.0f);
        float fx0 = floorf(cx), fy0 = floorf(cy);
        float fx = cx - fx0, fy = cy - fy0;
        int qi = (int)fy0 * QW + (int)fx0 + (QW + 1);
        uint2 q = quad[qi];
        float v00 = __builtin_bit_cast(float, q.x << 16);
        float v01 = __builtin_bit_cast(float, q.x & 0xffff0000u);
        float v10 = __builtin_bit_cast(float, q.y << 16);
        float v11 = __builtin_bit_cast(float, q.y & 0xffff0000u);
        float top = v00 + fx*(v01 - v00);
        float bot = v10 + fx*(v11 - v10);
        return top + fy*(bot - top);
    };

    float acc = 0.f;
    int j = jlo + lane;
    float s0 = (float)(j - 364);
    float px1 = bx - s0*sn,          py1 = by + s0*cs;
    float px2 = px1 - 64.0f*sn,      py2 = py1 + 64.0f*cs;
    float dx128 = -128.0f*sn,        dy128 = 128.0f*cs;
    for (; j + 64 <= jhi; j += 128) {
        acc += samp(px1, py1) + samp(px2, py2);
        px1 += dx128; py1 += dy128;
        px2 += dx128; py2 += dy128;
    }
    if (j <= jhi) acc += samp(px1, py1);

    for (int off = 32; off; off >>= 1) acc += __shfl_down(acc, off);
    if (lane == 0) sino[idx] = acc;
}

// ---------------- ramp filter (direct conv == FFT path) + subtract measurement ----------------
__global__ __launch_bounds__(256) void filter_k(const float* __restrict__ sino,
        const float* __restrict__ meas, float* __restrict__ diff) {
    __shared__ float prow[DET + 2*728];
    __shared__ float invsq[364];
    int a = blockIdx.x / 3, seg = blockIdx.x - 3*a;
    for (int t = threadIdx.x; t < DET + 2*728; t += 256)
        prow[t] = (t >= 728 && t < 728 + DET) ? sino[a*DET + (t - 728)] : 0.f;
    const float cc = -2.0f / (3.14159265358979323846f * 3.14159265358979323846f);
    for (int k = threadIdx.x; k < 364; k += 256) {
        float dlt = (float)(2*k + 1);
        invsq[k] = cc / (dlt * dlt);
    }
    __syncthreads();
    const float scale = 3.14159265358979323846f / 180.0f;  // pi/(2*90)
    int i = seg*243 + threadIdx.x;
    if (threadIdx.x < 243) {
        const float* p = prow + 728 + i;
        float acc = 0.5f * p[0];
        #pragma unroll 4
        for (int k = 0; k < 364; k++) {
            int dlt = 2*k + 1;
            acc += (p[-dlt] + p[dlt]) * invsq[k];
        }
        diff[a*DET + i] = acc * scale - meas[a*DET + i];
    }
}

// ---------------- build float2 pairs (diff[i], diff[i+1]) for backprojection ----------------
__global__ void pair_k(const float* __restrict__ diff, float2* __restrict__ pair) {
    int i = blockIdx.x * 256 + threadIdx.x;
    if (i >= NA*DET) return;
    int col = i - (i / DET) * DET;
    float b = (col == DET-1) ? 0.f : diff[i + 1];
    pair[i] = make_float2(diff[i], b);
}

// ---------------- backprojection fused with x_input = x - lambda*bp ----------------
__global__ __launch_bounds__(256) void backproj_k(const float2* __restrict__ pair,
        const float* __restrict__ trig, const float* __restrict__ x,
        const float* __restrict__ lam, float* __restrict__ xin) {
    int pix = blockIdx.x * 256 + threadIdx.x;
    float X = (float)(pix & 511) - 255.5f;
    float Y = (float)(pix >> 9) - 255.5f;
    float acc = 0.f;
    for (int a = 0; a < NA; a++) {
        float pos = X*trig[2*a] + Y*trig[2*a+1] + 364.0f;
        if (pos >= 0.f && pos <= 728.f) {
            int i0 = (int)pos;
            if (i0 > 727) i0 = 727;
            float w = pos - (float)i0;
            float2 p = pair[a*DET + i0];
            acc += p.x + w*(p.y - p.x);
        }
    }
    xin[pix] = x[pix] - lam[0] * acc;
}

// ---------------- prep1: halo zeroing + convM weights + convG padded weights ----------------
__global__ void prep1_k(unsigned short* __restrict__ hb0, size_t hbstride_elems,
                        const float* __restrict__ w0, const float* __restrict__ w1,
                        const float* __restrict__ w2, const float* __restrict__ w3,
                        const float* __restrict__ wg4,
                        unsigned short* __restrict__ wbuf) {
    int t = blockIdx.x * 256 + threadIdx.x;
    if (t < 4*2052) {
        int b = t / 2052, r = t - b*2052;
        int py, px;
        if      (r < 514)  { py = 0;            px = r; }
        else if (r < 1028) { py = 513;          px = r - 514; }
        else if (r < 1540) { py = r - 1028 + 1; px = 0; }
        else               { py = r - 1540 + 1; px = 513; }
        unsigned short* p = hb0 + b*hbstride_elems + ((size_t)py*HW + px)*32;
        uint4 z = make_uint4(0,0,0,0);
        ((uint4*)p)[0] = z; ((uint4*)p)[1] = z; ((uint4*)p)[2] = z; ((uint4*)p)[3] = z;
        return;
    }
    int tid = t - 4*2052;
    if (tid < 4*9216) {
        int L = tid / 9216, r = tid - L*9216;
        int tt = r >> 10, o = (r >> 5) & 31, i = r & 31;
        const float* s = (L == 0) ? w0 : (L == 1) ? w1 : (L == 2) ? w2 : w3;
        wbuf[tid] = f2b(s[o*288 + i*9 + tt]);
        return;
    }
    int gid = tid - 4*9216;                 // wG padded: [tap][16 oc][32 ic], oc0 real
    if (gid >= 9*512) return;
    int tt = gid / 512, r = gid - tt*512;
    int o = r >> 5, i = r & 31;
    wbuf[4*9216 + gid] = (o == 0) ? f2b(wg4[i*9 + tt]) : (unsigned short)0;
}

// ---------------- conv_D: 1 -> 32, f32 direct; writes bf16 NHWC halo'd ----------------
__global__ __launch_bounds__(256) void convD_k(const float* __restrict__ xin,
        const float* __restrict__ wD, unsigned short* __restrict__ out_nhwc) {
    int pix = blockIdx.x * 256 + threadIdx.x;
    int y = pix >> 9, x = pix & 511;
    float v[9];
    #pragma unroll
    for (int dy = -1; dy <= 1; dy++)
        #pragma unroll
        for (int dx = -1; dx <= 1; dx++) {
            int yy = y + dy, xx = x + dx;
            v[(dy+1)*3 + dx+1] = (yy >= 0 && yy < 512 && xx >= 0 && xx < 512)
                                 ? xin[(yy << 9) + xx] : 0.f;
        }
    unsigned int packed[16];
    #pragma unroll
    for (int oc = 0; oc < 32; ++oc) {
        float acc = 0.f;
        #pragma unroll
        for (int t = 0; t < 9; t++) acc = fmaf(v[t], wD[oc*9 + t], acc);
        unsigned int b = f2b(acc);
        if (oc & 1) packed[oc >> 1] |= b << 16; else packed[oc >> 1] = b;
    }
    uint4* dst = (uint4*)(out_nhwc + ((size_t)(y+1)*HW + (x+1))*32);
    dst[0] = make_uint4(packed[0],  packed[1],  packed[2],  packed[3]);
    dst[1] = make_uint4(packed[4],  packed[5],  packed[6],  packed[7]);
    dst[2] = make_uint4(packed[8],  packed[9],  packed[10], packed[11]);
    dst[3] = make_uint4(packed[12], packed[13], packed[14], packed[15]);
}

// ---------------- MFMA conv 32->32, direct-global B-frags (round-3 form) ----------------
// MODE: 0 plain->out0 | 1 relu->out0 | 2 dual: raw->out0, softthr->out1
//       | 3 symloss: - aux(bf16 NHWC) -> s1,s2 (f32 NCHW)
template<int MODE>
__global__ __launch_bounds__(256) void convM_k(const unsigned short* __restrict__ in,
        const unsigned short* __restrict__ wb,
        unsigned short* __restrict__ out0, unsigned short* __restrict__ out1,
        const float* __restrict__ thr_p,
        const unsigned short* __restrict__ aux, float* __restrict__ s1, float* __restrict__ s2) {
    int wid  = threadIdx.x >> 6;
    int lane = threadIdx.x & 63;
    int by = blockIdx.x >> 3, bx = blockIdx.x & 7;
    int y  = by*4 + wid;          // 0..511
    int x0 = bx*64;
    int lpix = lane & 15;
    int k8   = (lane >> 4) * 8;

    bf16x8 A[9][2];
    #pragma unroll
    for (int t = 0; t < 9; t++)
        #pragma unroll
        for (int ob = 0; ob < 2; ob++)
            A[t][ob] = *(const bf16x8*)(wb + t*1024 + (ob*16 + lpix)*32 + k8);

    f32x4 acc[2][4];
    #pragma unroll
    for (int ob = 0; ob < 2; ob++)
        #pragma unroll
        for (int p = 0; p < 4; p++) acc[ob][p] = (f32x4){0.f,0.f,0.f,0.f};

    const short* base = (const short*)in + ((size_t)(y+1)*HW + (x0+1) + lpix)*32 + k8;
    #pragma unroll
    for (int dy = -1; dy <= 1; dy++)
        #pragma unroll
        for (int dx = -1; dx <= 1; dx++) {
            int t = (dy+1)*3 + (dx+1);
            const short* bp = base + (dy*HW + dx)*32;
            #pragma unroll
            for (int p = 0; p < 4; p++) {
                bf16x8 B = *(const bf16x8*)(bp + p*16*32);
                acc[0][p] = __builtin_amdgcn_mfma_f32_16x16x32_bf16(A[t][0], B, acc[0][p], 0,0,0);
                acc[1][p] = __builtin_amdgcn_mfma_f32_16x16x32_bf16(A[t][1], B, acc[1][p], 0,0,0);
            }
        }

    int prow = (lane >> 4) * 4;
    float thr = (MODE == 2) ? thr_p[0] : 0.f;
    #pragma unroll
    for (int ob = 0; ob < 2; ob++)
        #pragma unroll
        for (int p = 0; p < 4; p++) {
            f32x4 a = acc[ob][p];
            if (MODE == 3) {
                size_t aoff = ((size_t)(y+1)*HW + (x0 + 1 + p*16 + lpix))*32 + ob*16 + prow;
                ushort4 av = *(const ushort4*)(aux + aoff);
                int pix = (y << 9) + x0 + p*16 + lpix;
                float w0v = a[0] - b2f(av.x);
                float w1v = a[1] - b2f(av.y);
                float w2v = a[2] - b2f(av.z);
                float w3v = a[3] - b2f(av.w);
                int ocb = ob*16 + prow;
                s1[(size_t)(ocb+0)*NPIX + pix] = w0v; s2[(size_t)(ocb+0)*NPIX + pix] = w0v;
                s1[(size_t)(ocb+1)*NPIX + pix] = w1v; s2[(size_t)(ocb+1)*NPIX + pix] = w1v;
                s1[(size_t)(ocb+2)*NPIX + pix] = w2v; s2[(size_t)(ocb+2)*NPIX + pix] = w2v;
                s1[(size_t)(ocb+3)*NPIX + pix] = w3v; s2[(size_t)(ocb+3)*NPIX + pix] = w3v;
            } else {
                size_t off = ((size_t)(y+1)*HW + (x0 + 1 + p*16 + lpix))*32 + ob*16 + prow;
                if (MODE == 1) {
                    #pragma unroll
                    for (int r = 0; r < 4; r++) a[r] = fmaxf(a[r], 0.f);
                }
                *(ushort4*)(out0 + off) = make_ushort4(f2b(a[0]), f2b(a[1]), f2b(a[2]), f2b(a[3]));
                if (MODE == 2) {
                    float st[4];
                    #pragma unroll
                    for (int r = 0; r < 4; r++)
                        st[r] = copysignf(fmaxf(fabsf(a[r]) - thr, 0.f), a[r]);
                    *(ushort4*)(out1 + off) = make_ushort4(f2b(st[0]), f2b(st[1]), f2b(st[2]), f2b(st[3]));
                }
            }
        }
}

// ---------------- conv_G via MFMA: 32 -> 1 (A row 0 = wG), fused + xin ----------------
__global__ __launch_bounds__(256) void convGM_k(const unsigned short* __restrict__ in,
        const unsigned short* __restrict__ wg,      // [tap][16][32], oc0 real
        const float* __restrict__ xin, float* __restrict__ out) {
    int wid  = threadIdx.x >> 6;
    int lane = threadIdx.x & 63;
    int by = blockIdx.x >> 3, bx = blockIdx.x & 7;
    int y  = by*4 + wid;
    int x0 = bx*64;
    int lpix = lane & 15;
    int k8   = (lane >> 4) * 8;

    bf16x8 A[9];
    #pragma unroll
    for (int t = 0; t < 9; t++)
        A[t] = *(const bf16x8*)(wg + t*512 + lpix*32 + k8);

    f32x4 acc[4];
    #pragma unroll
    for (int p = 0; p < 4; p++) acc[p] = (f32x4){0.f,0.f,0.f,0.f};

    const short* base = (const short*)in + ((size_t)(y+1)*HW + (x0+1) + lpix)*32 + k8;
    #pragma unroll
    for (int dy = -1; dy <= 1; dy++)
        #pragma unroll
        for (int dx = -1; dx <= 1; dx++) {
            int t = (dy+1)*3 + (dx+1);
            const short* bp = base + (dy*HW + dx)*32;
            #pragma unroll
            for (int p = 0; p < 4; p++) {
                bf16x8 B = *(const bf16x8*)(bp + p*16*32);
                acc[p] = __builtin_amdgcn_mfma_f32_16x16x32_bf16(A[t], B, acc[p], 0,0,0);
            }
        }

    if (lane < 16) {
        #pragma unroll
        for (int p = 0; p < 4; p++) {
            int pix = (y << 9) + x0 + p*16 + lane;
            out[pix] = acc[p][0] + xin[pix];
        }
    }
}

extern "C" void kernel_launch(void* const* d_in, const int* in_sizes, int n_in,
                              void* d_out, int out_size, void* d_ws, size_t ws_size,
                              hipStream_t stream) {
    const float* x     = (const float*)d_in[0];
    const float* theta = (const float*)d_in[1];
    const float* meas  = (const float*)d_in[2];
    const float* lam   = (const float*)d_in[3];
    const float* thr   = (const float*)d_in[4];
    const float* wD    = (const float*)d_in[5];
    const float* w1f   = (const float*)d_in[6];
    const float* w2f   = (const float*)d_in[7];
    const float* w1b   = (const float*)d_in[8];
    const float* w2b   = (const float*)d_in[9];
    const float* wG    = (const float*)d_in[10];

    char* ws = (char*)d_ws;
    const size_t HBB = (size_t)HBELEMS * 2;          // bytes per halo'd bf16 buffer
    unsigned short* HB1 = (unsigned short*)(ws);
    unsigned short* HB2 = (unsigned short*)(ws + HBB);
    unsigned short* HB3 = (unsigned short*)(ws + 2*HBB);
    unsigned short* HB4 = (unsigned short*)(ws + 3*HBB);
    // radon scratch aliases: sino/diff/pair in HB2 (dead until h1), quad in HB3 (dead until xf)
    float*  sino  = (float*)(ws + HBB);
    float*  diff  = (float*)(ws + HBB + 262464);
    float2* dpair = (float2*)(ws + HBB + 524928);
    uint2*  quad  = (uint2*)(ws + 2*HBB);
    float* xin  = (float*)(ws + 4*HBB);
    float* trig = (float*)(ws + 4*HBB + 1048576);
    unsigned short* wbuf = (unsigned short*)(ws + 4*HBB + 1049600);
    unsigned short* wgbuf = wbuf + 4*9216;

    float* P  = (float*)d_out;        // x_pred  (NPIX)
    float* S1 = P + NPIX;             // symloss #1 (32*NPIX)
    float* S2 = S1 + 32*NPIX;         // symloss #2 (32*NPIX)

    prep0_k<<<1 + (QW*QW + 255)/256, 256, 0, stream>>>(theta, x, trig, quad);
    radon_fwd_k<<<(NA*DET + 3)/4, 256, 0, stream>>>(quad, trig, sino);
    filter_k<<<NA*3, 256, 0, stream>>>(sino, meas, diff);
    pair_k<<<(NA*DET + 255)/256, 256, 0, stream>>>(diff, dpair);
    backproj_k<<<NPIX/256, 256, 0, stream>>>(dpair, trig, x, lam, xin);
    prep1_k<<<(4*2052 + 4*9216 + 9*512 + 255)/256, 256, 0, stream>>>(HB1, HBELEMS,
                                             w1f, w2f, w1b, w2b, wG, wbuf);

    convD_k<<<NPIX/256, 256, 0, stream>>>(xin, wD, HB1);                           // x_D -> HB1 (persists)
    convM_k<1><<<1024, 256, 0, stream>>>(HB1, wbuf + 0*9216, HB2, nullptr,
                                         nullptr, nullptr, nullptr, nullptr);      // h1 -> HB2
    convM_k<2><<<1024, 256, 0, stream>>>(HB2, wbuf + 1*9216, HB3, HB4,
                                         thr, nullptr, nullptr, nullptr);          // xf -> HB3, st -> HB4
    convM_k<1><<<1024, 256, 0, stream>>>(HB4, wbuf + 2*9216, HB2, nullptr,
                                         nullptr, nullptr, nullptr, nullptr);      // h2 -> HB2
    convM_k<0><<<1024, 256, 0, stream>>>(HB2, wbuf + 3*9216, HB4, nullptr,
                                         nullptr, nullptr, nullptr, nullptr);      // xb -> HB4
    convGM_k<<<1024, 256, 0, stream>>>(HB4, wgbuf, xin, P);                        // x_pred
    convM_k<1><<<1024, 256, 0, stream>>>(HB3, wbuf + 2*9216, HB2, nullptr,
                                         nullptr, nullptr, nullptr, nullptr);      // h3 -> HB2
    convM_k<3><<<1024, 256, 0, stream>>>(HB2, wbuf + 3*9216, nullptr, nullptr,
                                         nullptr, HB1, S1, S2);                    // symloss
}